// Round 12
// baseline (25069.397 us; speedup 1.0000x reference)
//
#include <hip/hip_runtime.h>
#include <cstdint>
#include <cstddef>

#define TT 8192
#define DD 512
#define MM 2048   // M1 == M2
#define KK 1024

typedef float f32x4 __attribute__((ext_vector_type(4)));
typedef int   i32x4 __attribute__((ext_vector_type(4)));
typedef int   i32x2 __attribute__((ext_vector_type(2)));
typedef unsigned int uint32;

// ---------- coherent (L3 / coherence-point) memory helpers ----------
// sc0 sc1 bypasses L1+L2 on gfx950; reads/writes meet at memory-side L3.
// All asm VMEM is self-contained (load + vmcnt(0) in ONE block) — R7/R10 rule.
__device__ __forceinline__ void coh_load16(const uint32* p, i32x4& a) {
  asm volatile("global_load_dwordx4 %0, %1, off sc0 sc1\n\t"
               "s_waitcnt vmcnt(0)"
               : "=v"(a) : "v"(p) : "memory");
}
__device__ __forceinline__ void coh_load32(const uint32* p, i32x4& a, i32x4& b) {
  asm volatile("global_load_dwordx4 %0, %2, off sc0 sc1\n\t"
               "global_load_dwordx4 %1, %2, off offset:16 sc0 sc1\n\t"
               "s_waitcnt vmcnt(0)"
               : "=v"(a), "=v"(b) : "v"(p) : "memory");
}
__device__ __forceinline__ void coh_store8(uint32* p, i32x2 v) {
  asm volatile("global_store_dwordx2 %0, %1, off sc0 sc1" :: "v"(p), "v"(v) : "memory");
}
__device__ __forceinline__ void coh_store32(uint32* p, i32x4 a, i32x4 b) {
  asm volatile("global_store_dwordx4 %0, %1, off sc0 sc1\n\t"
               "global_store_dwordx4 %0, %2, off offset:16 sc0 sc1"
               :: "v"(p), "v"(a), "v"(b) : "memory");
}

__device__ __forceinline__ int sent4(i32x4 a) {  // any bf16 sign bit set?
  return ((a.x | a.y | a.z | a.w) & 0x80008000u) != 0;
}
__device__ __forceinline__ float scrub(float v) {
  return __int_as_float(__float_as_int(v) & 0x7fffffff);
}
__device__ __forceinline__ uint32 bf16r(float f) {  // RNE bf16 (low 16 bits)
  uint32 u = __float_as_uint(f);
  return (u + 0x7fffu + ((u >> 16) & 1u)) >> 16;
}
__device__ __forceinline__ uint32 pack2(float lo, float hi) {
  return bf16r(lo) | (bf16r(hi) << 16);
}
__device__ __forceinline__ float bflo(uint32 u) { return __uint_as_float(u << 16); }
__device__ __forceinline__ float bfhi(uint32 u) { return __uint_as_float(u & 0xffff0000u); }

// ---------- fp32 tiled GEMM: C[M,N] = A[M,K] @ B[K,N] + bias[N] ----------
__global__ void __launch_bounds__(256) gemm_bias_f32(
    const float* __restrict__ A, const float* __restrict__ B,
    const float* __restrict__ bias, float* __restrict__ C,
    int M, int N, int K)
{
  __shared__ float As[16][128];
  __shared__ float Bs[16][128];
  const int tid = threadIdx.x;
  const int tx = tid & 15, ty = tid >> 4;
  const int row0 = blockIdx.y * 128, col0 = blockIdx.x * 128;
  const int arow = tid >> 1;
  const int ak0  = (tid & 1) * 8;
  const int brow = tid >> 4;
  const int bcol = (tid & 15) * 8;

  const float* Aptr = A + (size_t)(row0 + arow) * K + ak0;
  const float* Bptr = B + (size_t)brow * N + col0 + bcol;

  float acc[8][8];
  #pragma unroll
  for (int i = 0; i < 8; ++i)
    #pragma unroll
    for (int j = 0; j < 8; ++j) acc[i][j] = 0.f;

  for (int kk = 0; kk < K; kk += 16) {
    float4 a0 = *(const float4*)(Aptr + kk);
    float4 a1 = *(const float4*)(Aptr + kk + 4);
    float4 b0 = *(const float4*)(Bptr + (size_t)kk * N);
    float4 b1 = *(const float4*)(Bptr + (size_t)kk * N + 4);
    __syncthreads();
    As[ak0+0][arow] = a0.x; As[ak0+1][arow] = a0.y;
    As[ak0+2][arow] = a0.z; As[ak0+3][arow] = a0.w;
    As[ak0+4][arow] = a1.x; As[ak0+5][arow] = a1.y;
    As[ak0+6][arow] = a1.z; As[ak0+7][arow] = a1.w;
    *(float4*)&Bs[brow][bcol]     = b0;
    *(float4*)&Bs[brow][bcol + 4] = b1;
    __syncthreads();
    #pragma unroll
    for (int k = 0; k < 16; ++k) {
      float4 av0 = *(float4*)&As[k][ty*8];
      float4 av1 = *(float4*)&As[k][ty*8 + 4];
      float4 bv0 = *(float4*)&Bs[k][tx*4];
      float4 bv1 = *(float4*)&Bs[k][64 + tx*4];
      float ar[8] = {av0.x,av0.y,av0.z,av0.w,av1.x,av1.y,av1.z,av1.w};
      float br[8] = {bv0.x,bv0.y,bv0.z,bv0.w,bv1.x,bv1.y,bv1.z,bv1.w};
      #pragma unroll
      for (int i = 0; i < 8; ++i)
        #pragma unroll
        for (int j = 0; j < 8; ++j)
          acc[i][j] += ar[i] * br[j];
    }
  }

  float4 bi0 = *(const float4*)&bias[col0 + tx*4];
  float4 bi1 = *(const float4*)&bias[col0 + 64 + tx*4];
  #pragma unroll
  for (int i = 0; i < 8; ++i) {
    size_t r = (size_t)(row0 + ty*8 + i) * N;
    float4 o0 = make_float4(acc[i][0]+bi0.x, acc[i][1]+bi0.y, acc[i][2]+bi0.z, acc[i][3]+bi0.w);
    float4 o1 = make_float4(acc[i][4]+bi1.x, acc[i][5]+bi1.y, acc[i][6]+bi1.z, acc[i][7]+bi1.w);
    *(float4*)&C[r + col0 + tx*4]      = o0;
    *(float4*)&C[r + col0 + 64 + tx*4] = o1;
  }
}

// ---------- fused 2-layer pipelined scan, bf16 transport ----------
// H1b/H2b rows: 1024 dwords; dword j = cols {2j,2j+1} bf16.
// PUBLISH: lane0 of each wave stores its 4 cols as ONE 8B dwordx2 right after
// the shuffle reduce (atomic granule; no hout funnel, no pre-publish barrier).
// POLL: all 256 threads poll one dwordx4 (16B, 4-dword sentinel) + sleep(1).
__global__ void __launch_bounds__(256, 1) rnn_fused(
    const float* __restrict__ Xp1, uint32* __restrict__ H1b,
    uint32* __restrict__ H2b, float* __restrict__ H2f,
    const float* __restrict__ Wh1, const float* __restrict__ Wx2,
    const float* __restrict__ Wh2, const float* __restrict__ h01,
    const float* __restrict__ h02, const float* __restrict__ bh2)
{
  __shared__ __align__(16) unsigned char smem[143360];
  const int tid  = threadIdx.x;
  const int lane = tid & 63;
  const int wv   = tid >> 6;       // wave 0..3, owns 4 cols

  if (blockIdx.x < 128) {
    // ================= layer 1 =================
    const int w = blockIdx.x;
    float*  WL  = (float*)smem;                 // [16][2048] fp32, [col][k]
    uint32* h1p = (uint32*)(smem + 131072);     // [1024] packed row

    for (int r = 0; r < 8; ++r) {
      const int k = tid + 256*r;
      const float* src = &Wh1[(size_t)k*MM + 16*w];
      #pragma unroll
      for (int c4 = 0; c4 < 4; ++c4) {
        float4 q = *(const float4*)(src + 4*c4);
        WL[(4*c4+0)*2048 + k] = q.x;
        WL[(4*c4+1)*2048 + k] = q.y;
        WL[(4*c4+2)*2048 + k] = q.z;
        WL[(4*c4+3)*2048 + k] = q.w;
      }
    }
    const int cbase = 16*w + 4*wv;
    f32x4 xc = {0.f,0.f,0.f,0.f}, xn = xc;
    if (lane == 0) xc = *(const f32x4*)&Xp1[cbase];
    __syncthreads();

    for (int t = 0; t < TT; ++t) {
      // ---- stage h1_{t-1}: each thread one 16B granule ----
      if (t == 0) {
        float4 e0 = ((const float4*)h01)[2*tid];
        float4 e1 = ((const float4*)h01)[2*tid + 1];
        uint32 d[4] = {pack2(e0.x,e0.y), pack2(e0.z,e0.w),
                       pack2(e1.x,e1.y), pack2(e1.z,e1.w)};
        *(i32x4*)&h1p[4*tid] = *(i32x4*)&d[0];
      } else {
        const uint32* src = H1b + (size_t)(t-1)*1024 + 4*tid;
        i32x4 a;
        for (;;) {
          coh_load16(src, a);
          if (!sent4(a)) break;
          __builtin_amdgcn_s_sleep(1);
        }
        *(i32x4*)&h1p[4*tid] = a;
      }
      if (lane == 0 && t + 1 < TT)
        xn = *(const f32x4*)&Xp1[(size_t)(t+1)*MM + cbase];
      __syncthreads();   // staging barrier

      float s0=0.f, s1=0.f, s2=0.f, s3=0.f;
      #pragma unroll
      for (int i = 0; i < 8; ++i) {
        const int k0 = 4*lane + 256*i;
        uint2 dw = *(uint2*)&h1p[k0 >> 1];
        f32x4 h = {bflo(dw.x), bfhi(dw.x), bflo(dw.y), bfhi(dw.y)};
        f32x4 q0 = *(f32x4*)&WL[(4*wv+0)*2048 + k0];
        f32x4 q1 = *(f32x4*)&WL[(4*wv+1)*2048 + k0];
        f32x4 q2 = *(f32x4*)&WL[(4*wv+2)*2048 + k0];
        f32x4 q3 = *(f32x4*)&WL[(4*wv+3)*2048 + k0];
        s0 += h.x*q0.x + h.y*q0.y + h.z*q0.z + h.w*q0.w;
        s1 += h.x*q1.x + h.y*q1.y + h.z*q1.z + h.w*q1.w;
        s2 += h.x*q2.x + h.y*q2.y + h.z*q2.z + h.w*q2.w;
        s3 += h.x*q3.x + h.y*q3.y + h.z*q3.z + h.w*q3.w;
      }
      #pragma unroll
      for (int off = 32; off; off >>= 1) {
        s0 += __shfl_xor(s0, off); s1 += __shfl_xor(s1, off);
        s2 += __shfl_xor(s2, off); s3 += __shfl_xor(s3, off);
      }
      // ---- per-wave direct publish (straight out of the reduce) ----
      if (lane == 0) {
        float y0 = scrub(fmaxf(xc.x + s0, 0.f));
        float y1 = scrub(fmaxf(xc.y + s1, 0.f));
        float y2 = scrub(fmaxf(xc.z + s2, 0.f));
        float y3 = scrub(fmaxf(xc.w + s3, 0.f));
        i32x2 d; d.x = (int)pack2(y0, y1); d.y = (int)pack2(y2, y3);
        coh_store8(H1b + (size_t)t*1024 + 8*w + 2*wv, d);
        xc = xn;
      }
      __syncthreads();   // WAR: protect h1p against next step's staging
    }
  } else {
    // ================= layer 2 =================
    const int w = blockIdx.x - 128;
    // W2p: col-pair packed bf16: elem cp*8192 + 2k + (c&1), cp=c>>1, k in [0,4096)
    unsigned short* W2p  = (unsigned short*)smem;      // 128KB
    uint32* h1buf0 = (uint32*)(smem + 131072);         // [1024]
    uint32* h1buf1 = (uint32*)(smem + 135168);         // [1024]
    uint32* h2p    = (uint32*)(smem + 139264);         // [1024]

    for (int r = 0; r < 16; ++r) {
      const int k = tid + 256*r;
      const float* src = (k < MM) ? &Wx2[(size_t)k*MM + 16*w]
                                  : &Wh2[(size_t)(k-MM)*MM + 16*w];
      #pragma unroll
      for (int c4 = 0; c4 < 4; ++c4) {
        float4 q = *(const float4*)(src + 4*c4);
        const int c = 4*c4;
        W2p[((c+0)>>1)*8192 + 2*k + ((c+0)&1)] = (unsigned short)bf16r(q.x);
        W2p[((c+1)>>1)*8192 + 2*k + ((c+1)&1)] = (unsigned short)bf16r(q.y);
        W2p[((c+2)>>1)*8192 + 2*k + ((c+2)&1)] = (unsigned short)bf16r(q.z);
        W2p[((c+3)>>1)*8192 + 2*k + ((c+3)&1)] = (unsigned short)bf16r(q.w);
      }
    }
    const int cbase = 16*w + 4*wv;
    f32x4 bv = {0.f,0.f,0.f,0.f};
    if (lane == 0) bv = *(const f32x4*)&bh2[cbase];
    __syncthreads();

    // prologue: stage h1_0 into buf0 (16B granule per thread)
    {
      const uint32* p1 = H1b + 4*tid;
      i32x4 a;
      for (;;) {
        coh_load16(p1, a);
        if (!sent4(a)) break;
        __builtin_amdgcn_s_sleep(1);
      }
      *(i32x4*)&h1buf0[4*tid] = a;
    }
    __syncthreads();

    const int cp0 = 2*wv;   // col pairs (local cols 4wv..4wv+3)

    for (int t = 0; t < TT; ++t) {
      uint32* bufc = (t & 1) ? h1buf1 : h1buf0;
      uint32* bufn = (t & 1) ? h1buf0 : h1buf1;

      // ---- part A: h1-half of the dot (h2_{t-1} propagates underneath) ----
      float s0=0.f, s1=0.f, s2=0.f, s3=0.f;
      #pragma unroll
      for (int i = 0; i < 8; ++i) {
        const int k0 = 4*lane + 256*i;
        uint2 dw = *(uint2*)&bufc[k0 >> 1];
        f32x4 h = {bflo(dw.x), bfhi(dw.x), bflo(dw.y), bfhi(dw.y)};
        uint4 qa = *(uint4*)&W2p[(cp0+0)*8192 + 2*k0];
        uint4 qb = *(uint4*)&W2p[(cp0+1)*8192 + 2*k0];
        s0 += h.x*bflo(qa.x) + h.y*bflo(qa.y) + h.z*bflo(qa.z) + h.w*bflo(qa.w);
        s1 += h.x*bfhi(qa.x) + h.y*bfhi(qa.y) + h.z*bfhi(qa.z) + h.w*bfhi(qa.w);
        s2 += h.x*bflo(qb.x) + h.y*bflo(qb.y) + h.z*bflo(qb.z) + h.w*bflo(qb.w);
        s3 += h.x*bfhi(qb.x) + h.y*bfhi(qb.y) + h.z*bfhi(qb.z) + h.w*bfhi(qb.w);
      }

      // ---- stage h2_{t-1} (16B granule per thread) ----
      if (t == 0) {
        float4 e0 = ((const float4*)h02)[2*tid];
        float4 e1 = ((const float4*)h02)[2*tid + 1];
        uint32 d[4] = {pack2(e0.x,e0.y), pack2(e0.z,e0.w),
                       pack2(e1.x,e1.y), pack2(e1.z,e1.w)};
        *(i32x4*)&h2p[4*tid] = *(i32x4*)&d[0];
      } else {
        const uint32* p2 = H2b + (size_t)(t-1)*1024 + 4*tid;
        i32x4 c;
        for (;;) {
          coh_load16(p2, c);
          if (!sent4(c)) break;
          __builtin_amdgcn_s_sleep(1);
        }
        *(i32x4*)&h2p[4*tid] = c;
      }
      __syncthreads();   // barrier A

      // ---- part B: h2-half of the dot ----
      #pragma unroll
      for (int i = 0; i < 8; ++i) {
        const int k0 = 4*lane + 256*i;
        const int kw = 2048 + k0;
        uint2 dw = *(uint2*)&h2p[k0 >> 1];
        f32x4 h = {bflo(dw.x), bfhi(dw.x), bflo(dw.y), bfhi(dw.y)};
        uint4 qa = *(uint4*)&W2p[(cp0+0)*8192 + 2*kw];
        uint4 qb = *(uint4*)&W2p[(cp0+1)*8192 + 2*kw];
        s0 += h.x*bflo(qa.x) + h.y*bflo(qa.y) + h.z*bflo(qa.z) + h.w*bflo(qa.w);
        s1 += h.x*bfhi(qa.x) + h.y*bfhi(qa.y) + h.z*bfhi(qa.z) + h.w*bfhi(qa.w);
        s2 += h.x*bflo(qb.x) + h.y*bflo(qb.y) + h.z*bflo(qb.z) + h.w*bflo(qb.w);
        s3 += h.x*bfhi(qb.x) + h.y*bfhi(qb.y) + h.z*bfhi(qb.z) + h.w*bfhi(qb.w);
      }
      #pragma unroll
      for (int off = 32; off; off >>= 1) {
        s0 += __shfl_xor(s0, off); s1 += __shfl_xor(s1, off);
        s2 += __shfl_xor(s2, off); s3 += __shfl_xor(s3, off);
      }
      // ---- per-wave direct publish ----
      if (lane == 0) {
        float y0 = scrub(fmaxf(s0 + bv.x, 0.f));
        float y1 = scrub(fmaxf(s1 + bv.y, 0.f));
        float y2 = scrub(fmaxf(s2 + bv.z, 0.f));
        float y3 = scrub(fmaxf(s3 + bv.w, 0.f));
        i32x2 d; d.x = (int)pack2(y0, y1); d.y = (int)pack2(y2, y3);
        coh_store8(H2b + (size_t)t*1024 + 8*w + 2*wv, d);
        f32x4 y = {y0, y1, y2, y3};
        *(f32x4*)&H2f[(size_t)t*MM + cbase] = y;   // fp32 copy for logits GEMM
      }

      // ---- prefetch h1_{t+1} into bufn (hides under h2_t propagation) ----
      if (t + 1 < TT) {
        const uint32* p1 = H1b + (size_t)(t+1)*1024 + 4*tid;
        i32x4 a;
        for (;;) {
          coh_load16(p1, a);
          if (!sent4(a)) break;
          __builtin_amdgcn_s_sleep(1);
        }
        *(i32x4*)&bufn[4*tid] = a;
      }
      __syncthreads();   // barrier B
    }
  }
}

// ---------- fallback single-layer scan (R3, proven) ----------
__global__ void __launch_bounds__(256, 1) rnn_scan_f32(
    const float* __restrict__ Xp, float* __restrict__ H,
    const float* __restrict__ Wh, const float* __restrict__ h0)
{
  __shared__ float h_s[MM];
  __shared__ float h_out[8];
  const int tid  = threadIdx.x;
  const int wg   = blockIdx.x;
  const int lane = tid & 63;
  const int wv   = tid >> 6;
  const int c0   = wg * 8 + wv * 2;

  float4 w0[8], w1[8];
  #pragma unroll
  for (int i = 0; i < 8; ++i) {
    const int kb = lane*4 + 256*i;
    float2 e0 = *(const float2*)&Wh[(size_t)(kb+0)*MM + c0];
    float2 e1 = *(const float2*)&Wh[(size_t)(kb+1)*MM + c0];
    float2 e2 = *(const float2*)&Wh[(size_t)(kb+2)*MM + c0];
    float2 e3 = *(const float2*)&Wh[(size_t)(kb+3)*MM + c0];
    w0[i] = make_float4(e0.x, e1.x, e2.x, e3.x);
    w1[i] = make_float4(e0.y, e1.y, e2.y, e3.y);
  }

  for (int t = 0; t < TT; ++t) {
    float4 ha, hb;
    if (t == 0) {
      ha = ((const float4*)h0)[tid*2];
      hb = ((const float4*)h0)[tid*2 + 1];
    } else {
      const uint32* src = (const uint32*)(H + (size_t)(t-1)*MM + tid*8);
      i32x4 a, b;
      do { coh_load32(src, a, b); }
      while ((a.x | a.y | a.z | a.w | b.x | b.y | b.z | b.w) < 0);
      ha = make_float4(__int_as_float(a.x), __int_as_float(a.y),
                       __int_as_float(a.z), __int_as_float(a.w));
      hb = make_float4(__int_as_float(b.x), __int_as_float(b.y),
                       __int_as_float(b.z), __int_as_float(b.w));
    }
    float xv = 0.f;
    if (lane < 2) xv = Xp[(size_t)t*MM + c0 + lane];
    ((float4*)h_s)[tid*2]     = ha;
    ((float4*)h_s)[tid*2 + 1] = hb;
    __syncthreads();

    float s0 = 0.f, s1 = 0.f;
    #pragma unroll
    for (int i = 0; i < 8; ++i) {
      float4 h4 = *(float4*)&h_s[lane*4 + 256*i];
      s0 += h4.x*w0[i].x + h4.y*w0[i].y + h4.z*w0[i].z + h4.w*w0[i].w;
      s1 += h4.x*w1[i].x + h4.y*w1[i].y + h4.z*w1[i].z + h4.w*w1[i].w;
    }
    #pragma unroll
    for (int off = 32; off; off >>= 1) {
      s0 += __shfl_xor(s0, off);
      s1 += __shfl_xor(s1, off);
    }
    if (lane < 2) {
      float s = (lane == 0) ? s0 : s1;
      h_out[wv*2 + lane] = scrub(fmaxf(xv + s, 0.f));
    }
    __syncthreads();
    if (tid == 0) {
      i32x4 o0 = *(i32x4*)&h_out[0];
      i32x4 o1 = *(i32x4*)&h_out[4];
      coh_store32((uint32*)(H + (size_t)t*MM + wg*8), o0, o1);
    }
  }
}

extern "C" void kernel_launch(void* const* d_in, const int* in_sizes, int n_in,
                              void* d_out, int out_size, void* d_ws, size_t ws_size,
                              hipStream_t stream) {
  (void)in_sizes; (void)n_in; (void)out_size;

  const float* X   = (const float*)d_in[0];
  const float* Wx1 = (const float*)d_in[1];
  const float* Wh1 = (const float*)d_in[2];
  const float* bh1 = (const float*)d_in[3];
  const float* h01 = (const float*)d_in[4];
  const float* Wx2 = (const float*)d_in[5];
  const float* Wh2 = (const float*)d_in[6];
  const float* bh2 = (const float*)d_in[7];
  const float* h02 = (const float*)d_in[8];
  const float* Wl  = (const float*)d_in[9];
  const float* bl  = (const float*)d_in[10];
  float* out = (float*)d_out;

  const size_t NBUF = (size_t)TT * MM;
  dim3 blk(256);

  if (ws_size >= 3 * NBUF * sizeof(float)) {
    // layout: [Xp1 f32 64MB][H2f f32 64MB][H1b bf16 32MB][H2b bf16 32MB]
    float*  Xp1 = (float*)d_ws;
    float*  H2f = Xp1 + NBUF;
    uint32* H1b = (uint32*)(H2f + NBUF);
    uint32* H2b = H1b + (size_t)TT * 1024;

    (void)hipMemsetAsync(H1b, 0xFF, 2 * (size_t)TT * 1024 * sizeof(uint32), stream);

    gemm_bias_f32<<<dim3(MM/128, TT/128), blk, 0, stream>>>(X, Wx1, bh1, Xp1, TT, MM, DD);

    {
      const float* xp = Xp1; uint32* h1b = H1b; uint32* h2b = H2b; float* h2f = H2f;
      const float* wh1 = Wh1; const float* wx2 = Wx2; const float* wh2 = Wh2;
      const float* h01p = h01; const float* h02p = h02; const float* bh2p = bh2;
      void* args[] = {&xp, &h1b, &h2b, &h2f, &wh1, &wx2, &wh2, &h01p, &h02p, &bh2p};
      (void)hipLaunchCooperativeKernel((const void*)rnn_fused, dim3(256), blk, args, 0, stream);
    }

    gemm_bias_f32<<<dim3(KK/128, TT/128), blk, 0, stream>>>(H2f, Wl, bl, out, TT, KK, MM);
  } else {
    // ---- fallback: R3 two-scan path ----
    float* bufA = (float*)d_ws;
    float* bufB = bufA + NBUF;

    (void)hipMemsetAsync(bufB, 0xFF, NBUF * sizeof(float), stream);
    gemm_bias_f32<<<dim3(MM/128, TT/128), blk, 0, stream>>>(X, Wx1, bh1, bufA, TT, MM, DD);
    {
      const float* xp = bufA; float* h = bufB; const float* wh = Wh1; const float* h0p = h01;
      void* args[] = {&xp, &h, &wh, &h0p};
      (void)hipLaunchCooperativeKernel((const void*)rnn_scan_f32, dim3(256), blk, args, 0, stream);
    }
    gemm_bias_f32<<<dim3(MM/128, TT/128), blk, 0, stream>>>(bufB, Wx2, bh2, bufA, TT, MM, MM);
    (void)hipMemsetAsync(bufB, 0xFF, NBUF * sizeof(float), stream);
    {
      const float* xp = bufA; float* h = bufB; const float* wh = Wh2; const float* h0p = h02;
      void* args[] = {&xp, &h, &wh, &h0p};
      (void)hipLaunchCooperativeKernel((const void*)rnn_scan_f32, dim3(256), blk, args, 0, stream);
    }
    gemm_bias_f32<<<dim3(KK/128, TT/128), blk, 0, stream>>>(bufA, Wl, bl, out, TT, KK, MM);
  }
}

// Round 13
// 24096.300 us; speedup vs baseline: 1.0404x; 1.0404x over previous
//
#include <hip/hip_runtime.h>
#include <cstdint>
#include <cstddef>

#define TT 8192
#define DD 512
#define MM 2048   // M1 == M2
#define KK 1024

typedef float f32x4 __attribute__((ext_vector_type(4)));
typedef int   i32x4 __attribute__((ext_vector_type(4)));
typedef unsigned int uint32;

// ---------- coherent (L3 / coherence-point) memory helpers ----------
// sc0 sc1 bypasses L1+L2 on gfx950; reads/writes meet at memory-side L3,
// the only cache level coherent across XCDs (intra-kernel).
// Keep asm VMEM self-contained (load + vmcnt(0) in ONE block) — R7/R10 lesson.
__device__ __forceinline__ void coh_load32(const uint32* p, i32x4& a, i32x4& b) {
  asm volatile("global_load_dwordx4 %0, %2, off sc0 sc1\n\t"
               "global_load_dwordx4 %1, %2, off offset:16 sc0 sc1\n\t"
               "s_waitcnt vmcnt(0)"
               : "=v"(a), "=v"(b) : "v"(p) : "memory");
}
__device__ __forceinline__ void coh_store32(uint32* p, i32x4 a, i32x4 b) {
  asm volatile("global_store_dwordx4 %0, %1, off sc0 sc1\n\t"
               "global_store_dwordx4 %0, %2, off offset:16 sc0 sc1"
               :: "v"(p), "v"(a), "v"(b) : "memory");
}

__device__ __forceinline__ int sent8(i32x4 a, i32x4 b) {  // any bf16 sign bit set?
  return ((a.x|a.y|a.z|a.w|b.x|b.y|b.z|b.w) & 0x80008000u) != 0;
}
__device__ __forceinline__ float scrub(float v) {
  return __int_as_float(__float_as_int(v) & 0x7fffffff);
}
__device__ __forceinline__ uint32 bf16r(float f) {  // RNE bf16 (low 16 bits)
  uint32 u = __float_as_uint(f);
  return (u + 0x7fffu + ((u >> 16) & 1u)) >> 16;
}
__device__ __forceinline__ uint32 pack2(float lo, float hi) {
  return bf16r(lo) | (bf16r(hi) << 16);
}
__device__ __forceinline__ float bflo(uint32 u) { return __uint_as_float(u << 16); }
__device__ __forceinline__ float bfhi(uint32 u) { return __uint_as_float(u & 0xffff0000u); }

// ---------- fp32 tiled GEMM: C[M,N] = A[M,K] @ B[K,N] + bias[N] ----------
__global__ void __launch_bounds__(256) gemm_bias_f32(
    const float* __restrict__ A, const float* __restrict__ B,
    const float* __restrict__ bias, float* __restrict__ C,
    int M, int N, int K)
{
  __shared__ float As[16][128];
  __shared__ float Bs[16][128];
  const int tid = threadIdx.x;
  const int tx = tid & 15, ty = tid >> 4;
  const int row0 = blockIdx.y * 128, col0 = blockIdx.x * 128;
  const int arow = tid >> 1;
  const int ak0  = (tid & 1) * 8;
  const int brow = tid >> 4;
  const int bcol = (tid & 15) * 8;

  const float* Aptr = A + (size_t)(row0 + arow) * K + ak0;
  const float* Bptr = B + (size_t)brow * N + col0 + bcol;

  float acc[8][8];
  #pragma unroll
  for (int i = 0; i < 8; ++i)
    #pragma unroll
    for (int j = 0; j < 8; ++j) acc[i][j] = 0.f;

  for (int kk = 0; kk < K; kk += 16) {
    float4 a0 = *(const float4*)(Aptr + kk);
    float4 a1 = *(const float4*)(Aptr + kk + 4);
    float4 b0 = *(const float4*)(Bptr + (size_t)kk * N);
    float4 b1 = *(const float4*)(Bptr + (size_t)kk * N + 4);
    __syncthreads();
    As[ak0+0][arow] = a0.x; As[ak0+1][arow] = a0.y;
    As[ak0+2][arow] = a0.z; As[ak0+3][arow] = a0.w;
    As[ak0+4][arow] = a1.x; As[ak0+5][arow] = a1.y;
    As[ak0+6][arow] = a1.z; As[ak0+7][arow] = a1.w;
    *(float4*)&Bs[brow][bcol]     = b0;
    *(float4*)&Bs[brow][bcol + 4] = b1;
    __syncthreads();
    #pragma unroll
    for (int k = 0; k < 16; ++k) {
      float4 av0 = *(float4*)&As[k][ty*8];
      float4 av1 = *(float4*)&As[k][ty*8 + 4];
      float4 bv0 = *(float4*)&Bs[k][tx*4];
      float4 bv1 = *(float4*)&Bs[k][64 + tx*4];
      float ar[8] = {av0.x,av0.y,av0.z,av0.w,av1.x,av1.y,av1.z,av1.w};
      float br[8] = {bv0.x,bv0.y,bv0.z,bv0.w,bv1.x,bv1.y,bv1.z,bv1.w};
      #pragma unroll
      for (int i = 0; i < 8; ++i)
        #pragma unroll
        for (int j = 0; j < 8; ++j)
          acc[i][j] += ar[i] * br[j];
    }
  }

  float4 bi0 = *(const float4*)&bias[col0 + tx*4];
  float4 bi1 = *(const float4*)&bias[col0 + 64 + tx*4];
  #pragma unroll
  for (int i = 0; i < 8; ++i) {
    size_t r = (size_t)(row0 + ty*8 + i) * N;
    float4 o0 = make_float4(acc[i][0]+bi0.x, acc[i][1]+bi0.y, acc[i][2]+bi0.z, acc[i][3]+bi0.w);
    float4 o1 = make_float4(acc[i][4]+bi1.x, acc[i][5]+bi1.y, acc[i][6]+bi1.z, acc[i][7]+bi1.w);
    *(float4*)&C[r + col0 + tx*4]      = o0;
    *(float4*)&C[r + col0 + 64 + tx*4] = o1;
  }
}

// ---------- fused 2-layer pipelined scan, bf16-packed hidden transport ----------
// H1b/H2b rows: 1024 dwords, dword j = cols {2j lo, 2j+1 hi} (bf16).
// Producer WG w owns cols [16w,16w+16) = dwords [8w,8w+8) = ONE 32B granule.
// Consumers: threads 0..127 each poll one granule, stage packed into LDS;
// dots unpack bf16 inline. Layer 2 also writes fp32 h2 (regular stores) for
// the downstream logits GEMM.
__global__ void __launch_bounds__(256, 1) rnn_fused(
    const float* __restrict__ Xp1, uint32* __restrict__ H1b,
    uint32* __restrict__ H2b, float* __restrict__ H2f,
    const float* __restrict__ Wh1, const float* __restrict__ Wx2,
    const float* __restrict__ Wh2, const float* __restrict__ h01,
    const float* __restrict__ h02, const float* __restrict__ bh2)
{
  __shared__ __align__(16) unsigned char smem[139392];
  const int tid  = threadIdx.x;
  const int lane = tid & 63;
  const int wv   = tid >> 6;       // wave 0..3, owns 4 cols

  if (blockIdx.x < 128) {
    // ================= layer 1 =================
    const int w = blockIdx.x;
    float*  WL   = (float*)smem;                 // [16][2048] fp32, [col][k]
    uint32* h1p  = (uint32*)(smem + 131072);     // [1024] packed bf16 row
    float*  hout = (float*)(smem + 135168);      // [16]

    for (int r = 0; r < 8; ++r) {
      const int k = tid + 256*r;
      const float* src = &Wh1[(size_t)k*MM + 16*w];
      #pragma unroll
      for (int c4 = 0; c4 < 4; ++c4) {
        float4 q = *(const float4*)(src + 4*c4);
        WL[(4*c4+0)*2048 + k] = q.x;
        WL[(4*c4+1)*2048 + k] = q.y;
        WL[(4*c4+2)*2048 + k] = q.z;
        WL[(4*c4+3)*2048 + k] = q.w;
      }
    }
    const int cbase = 16*w + 4*wv;
    f32x4 xc = {0.f,0.f,0.f,0.f}, xn = xc;
    if (lane == 0) xc = *(const f32x4*)&Xp1[cbase];
    __syncthreads();

    for (int t = 0; t < TT; ++t) {
      if (tid < 128) {
        const int g = tid;
        if (t == 0) {
          uint32 d[8];
          #pragma unroll
          for (int j = 0; j < 8; ++j)
            d[j] = pack2(h01[16*g + 2*j], h01[16*g + 2*j + 1]);
          *(i32x4*)&h1p[8*g]     = *(i32x4*)&d[0];
          *(i32x4*)&h1p[8*g + 4] = *(i32x4*)&d[4];
        } else {
          const uint32* src = H1b + (size_t)(t-1)*1024 + 8*g;
          i32x4 a, b;
          do { coh_load32(src, a, b); } while (sent8(a, b));
          *(i32x4*)&h1p[8*g]     = a;
          *(i32x4*)&h1p[8*g + 4] = b;
        }
      }
      if (lane == 0 && t + 1 < TT)
        xn = *(const f32x4*)&Xp1[(size_t)(t+1)*MM + cbase];
      __syncthreads();

      float s0=0.f, s1=0.f, s2=0.f, s3=0.f;
      #pragma unroll
      for (int i = 0; i < 8; ++i) {
        const int k0 = 4*lane + 256*i;
        uint2 dw = *(uint2*)&h1p[k0 >> 1];
        f32x4 h = {bflo(dw.x), bfhi(dw.x), bflo(dw.y), bfhi(dw.y)};
        f32x4 q0 = *(f32x4*)&WL[(4*wv+0)*2048 + k0];
        f32x4 q1 = *(f32x4*)&WL[(4*wv+1)*2048 + k0];
        f32x4 q2 = *(f32x4*)&WL[(4*wv+2)*2048 + k0];
        f32x4 q3 = *(f32x4*)&WL[(4*wv+3)*2048 + k0];
        s0 += h.x*q0.x + h.y*q0.y + h.z*q0.z + h.w*q0.w;
        s1 += h.x*q1.x + h.y*q1.y + h.z*q1.z + h.w*q1.w;
        s2 += h.x*q2.x + h.y*q2.y + h.z*q2.z + h.w*q2.w;
        s3 += h.x*q3.x + h.y*q3.y + h.z*q3.z + h.w*q3.w;
      }
      #pragma unroll
      for (int off = 32; off; off >>= 1) {
        s0 += __shfl_xor(s0, off); s1 += __shfl_xor(s1, off);
        s2 += __shfl_xor(s2, off); s3 += __shfl_xor(s3, off);
      }
      if (lane == 0) {
        f32x4 y;
        y.x = scrub(fmaxf(xc.x + s0, 0.f));
        y.y = scrub(fmaxf(xc.y + s1, 0.f));
        y.z = scrub(fmaxf(xc.z + s2, 0.f));
        y.w = scrub(fmaxf(xc.w + s3, 0.f));
        *(f32x4*)&hout[4*wv] = y;
        xc = xn;
      }
      __syncthreads();

      if (tid == 0) {
        uint32 d[8];
        #pragma unroll
        for (int j = 0; j < 8; ++j) d[j] = pack2(hout[2*j], hout[2*j+1]);
        coh_store32(H1b + (size_t)t*1024 + 8*w, *(i32x4*)&d[0], *(i32x4*)&d[4]);
      }
    }
  } else {
    // ================= layer 2 =================
    const int w = blockIdx.x - 128;
    // W2p: col-pair packed bf16: elem cp*8192 + 2k + (c&1), cp=c>>1, k in [0,4096)
    unsigned short* W2p = (unsigned short*)smem;      // 128KB
    uint32* h1p  = (uint32*)(smem + 131072);          // [1024]
    uint32* h2p  = (uint32*)(smem + 135168);          // [1024]
    float*  hout = (float*)(smem + 139264);           // [16]

    for (int r = 0; r < 16; ++r) {
      const int k = tid + 256*r;
      const float* src = (k < MM) ? &Wx2[(size_t)k*MM + 16*w]
                                  : &Wh2[(size_t)(k-MM)*MM + 16*w];
      #pragma unroll
      for (int c4 = 0; c4 < 4; ++c4) {
        float4 q = *(const float4*)(src + 4*c4);
        const int c = 4*c4;
        W2p[((c+0)>>1)*8192 + 2*k + ((c+0)&1)] = (unsigned short)bf16r(q.x);
        W2p[((c+1)>>1)*8192 + 2*k + ((c+1)&1)] = (unsigned short)bf16r(q.y);
        W2p[((c+2)>>1)*8192 + 2*k + ((c+2)&1)] = (unsigned short)bf16r(q.z);
        W2p[((c+3)>>1)*8192 + 2*k + ((c+3)&1)] = (unsigned short)bf16r(q.w);
      }
    }
    const int cbase = 16*w + 4*wv;
    f32x4 bv = {0.f,0.f,0.f,0.f};
    if (lane == 0) bv = *(const f32x4*)&bh2[cbase];
    __syncthreads();

    const int cp0 = 2*wv;   // col pairs cp0, cp0+1 (local cols 4wv..4wv+3)

    for (int t = 0; t < TT; ++t) {
      // ---- stage h1_t (packed; h1 chain leads) ----
      if (tid < 128) {
        const int g = tid;
        const uint32* p1 = H1b + (size_t)t*1024 + 8*g;
        i32x4 a, b;
        for (;;) {
          coh_load32(p1, a, b);
          if (!sent8(a, b)) break;
          __builtin_amdgcn_s_sleep(1);
        }
        *(i32x4*)&h1p[8*g]     = a;
        *(i32x4*)&h1p[8*g + 4] = b;
      }
      __syncthreads();

      // ---- part A: h1-half of the dot (hides h2 propagation) ----
      float s0=0.f, s1=0.f, s2=0.f, s3=0.f;
      #pragma unroll
      for (int i = 0; i < 8; ++i) {
        const int k0 = 4*lane + 256*i;
        uint2 dw = *(uint2*)&h1p[k0 >> 1];
        f32x4 h = {bflo(dw.x), bfhi(dw.x), bflo(dw.y), bfhi(dw.y)};
        uint4 qa = *(uint4*)&W2p[(cp0+0)*8192 + 2*k0];
        uint4 qb = *(uint4*)&W2p[(cp0+1)*8192 + 2*k0];
        s0 += h.x*bflo(qa.x) + h.y*bflo(qa.y) + h.z*bflo(qa.z) + h.w*bflo(qa.w);
        s1 += h.x*bfhi(qa.x) + h.y*bfhi(qa.y) + h.z*bfhi(qa.z) + h.w*bfhi(qa.w);
        s2 += h.x*bflo(qb.x) + h.y*bflo(qb.y) + h.z*bflo(qb.z) + h.w*bflo(qb.w);
        s3 += h.x*bfhi(qb.x) + h.y*bfhi(qb.y) + h.z*bfhi(qb.z) + h.w*bfhi(qb.w);
      }

      // ---- stage h2_{t-1} (propagated during part A) ----
      if (tid < 128) {
        const int g = tid;
        if (t == 0) {
          uint32 d[8];
          #pragma unroll
          for (int j = 0; j < 8; ++j)
            d[j] = pack2(h02[16*g + 2*j], h02[16*g + 2*j + 1]);
          *(i32x4*)&h2p[8*g]     = *(i32x4*)&d[0];
          *(i32x4*)&h2p[8*g + 4] = *(i32x4*)&d[4];
        } else {
          const uint32* p2 = H2b + (size_t)(t-1)*1024 + 8*g;
          i32x4 c, d;
          for (;;) {
            coh_load32(p2, c, d);
            if (!sent8(c, d)) break;
            __builtin_amdgcn_s_sleep(1);
          }
          *(i32x4*)&h2p[8*g]     = c;
          *(i32x4*)&h2p[8*g + 4] = d;
        }
      }
      __syncthreads();

      // ---- part B: h2-half of the dot ----
      #pragma unroll
      for (int i = 0; i < 8; ++i) {
        const int k0 = 4*lane + 256*i;
        const int kw = 2048 + k0;
        uint2 dw = *(uint2*)&h2p[k0 >> 1];
        f32x4 h = {bflo(dw.x), bfhi(dw.x), bflo(dw.y), bfhi(dw.y)};
        uint4 qa = *(uint4*)&W2p[(cp0+0)*8192 + 2*kw];
        uint4 qb = *(uint4*)&W2p[(cp0+1)*8192 + 2*kw];
        s0 += h.x*bflo(qa.x) + h.y*bflo(qa.y) + h.z*bflo(qa.z) + h.w*bflo(qa.w);
        s1 += h.x*bfhi(qa.x) + h.y*bfhi(qa.y) + h.z*bfhi(qa.z) + h.w*bfhi(qa.w);
        s2 += h.x*bflo(qb.x) + h.y*bflo(qb.y) + h.z*bflo(qb.z) + h.w*bflo(qb.w);
        s3 += h.x*bfhi(qb.x) + h.y*bfhi(qb.y) + h.z*bfhi(qb.z) + h.w*bfhi(qb.w);
      }
      #pragma unroll
      for (int off = 32; off; off >>= 1) {
        s0 += __shfl_xor(s0, off); s1 += __shfl_xor(s1, off);
        s2 += __shfl_xor(s2, off); s3 += __shfl_xor(s3, off);
      }
      if (lane == 0) {
        f32x4 y;
        y.x = scrub(fmaxf(s0 + bv.x, 0.f));
        y.y = scrub(fmaxf(s1 + bv.y, 0.f));
        y.z = scrub(fmaxf(s2 + bv.z, 0.f));
        y.w = scrub(fmaxf(s3 + bv.w, 0.f));
        *(f32x4*)&H2f[(size_t)t*MM + cbase] = y;   // fp32 copy for logits GEMM
        *(f32x4*)&hout[4*wv] = y;
      }
      __syncthreads();

      if (tid == 0) {
        uint32 d[8];
        #pragma unroll
        for (int j = 0; j < 8; ++j) d[j] = pack2(hout[2*j], hout[2*j+1]);
        coh_store32(H2b + (size_t)t*1024 + 8*w, *(i32x4*)&d[0], *(i32x4*)&d[4]);
      }
    }
  }
}

// ---------- fallback single-layer scan (R3, proven) ----------
__device__ __forceinline__ void coh_load2f(const int* p, i32x4& a, i32x4& b) {
  asm volatile("global_load_dwordx4 %0, %2, off sc0 sc1\n\t"
               "global_load_dwordx4 %1, %2, off offset:16 sc0 sc1\n\t"
               "s_waitcnt vmcnt(0)"
               : "=v"(a), "=v"(b) : "v"(p) : "memory");
}
__global__ void __launch_bounds__(256, 1) rnn_scan_f32(
    const float* __restrict__ Xp, float* __restrict__ H,
    const float* __restrict__ Wh, const float* __restrict__ h0)
{
  __shared__ float h_s[MM];
  __shared__ float h_out[8];
  const int tid  = threadIdx.x;
  const int wg   = blockIdx.x;
  const int lane = tid & 63;
  const int wv   = tid >> 6;
  const int c0   = wg * 8 + wv * 2;

  float4 w0[8], w1[8];
  #pragma unroll
  for (int i = 0; i < 8; ++i) {
    const int kb = lane*4 + 256*i;
    float2 e0 = *(const float2*)&Wh[(size_t)(kb+0)*MM + c0];
    float2 e1 = *(const float2*)&Wh[(size_t)(kb+1)*MM + c0];
    float2 e2 = *(const float2*)&Wh[(size_t)(kb+2)*MM + c0];
    float2 e3 = *(const float2*)&Wh[(size_t)(kb+3)*MM + c0];
    w0[i] = make_float4(e0.x, e1.x, e2.x, e3.x);
    w1[i] = make_float4(e0.y, e1.y, e2.y, e3.y);
  }

  for (int t = 0; t < TT; ++t) {
    float4 ha, hb;
    if (t == 0) {
      ha = ((const float4*)h0)[tid*2];
      hb = ((const float4*)h0)[tid*2 + 1];
    } else {
      const int* src = (const int*)(H + (size_t)(t-1)*MM + tid*8);
      i32x4 a, b;
      do { coh_load2f(src, a, b); }
      while ((a.x | a.y | a.z | a.w | b.x | b.y | b.z | b.w) < 0);
      ha = make_float4(__int_as_float(a.x), __int_as_float(a.y),
                       __int_as_float(a.z), __int_as_float(a.w));
      hb = make_float4(__int_as_float(b.x), __int_as_float(b.y),
                       __int_as_float(b.z), __int_as_float(b.w));
    }
    float xv = 0.f;
    if (lane < 2) xv = Xp[(size_t)t*MM + c0 + lane];
    ((float4*)h_s)[tid*2]     = ha;
    ((float4*)h_s)[tid*2 + 1] = hb;
    __syncthreads();

    float s0 = 0.f, s1 = 0.f;
    #pragma unroll
    for (int i = 0; i < 8; ++i) {
      float4 h4 = *(float4*)&h_s[lane*4 + 256*i];
      s0 += h4.x*w0[i].x + h4.y*w0[i].y + h4.z*w0[i].z + h4.w*w0[i].w;
      s1 += h4.x*w1[i].x + h4.y*w1[i].y + h4.z*w1[i].z + h4.w*w1[i].w;
    }
    #pragma unroll
    for (int off = 32; off; off >>= 1) {
      s0 += __shfl_xor(s0, off);
      s1 += __shfl_xor(s1, off);
    }
    if (lane < 2) {
      float s = (lane == 0) ? s0 : s1;
      h_out[wv*2 + lane] = scrub(fmaxf(xv + s, 0.f));
    }
    __syncthreads();
    if (tid == 0) {
      i32x4 o0 = *(i32x4*)&h_out[0];
      i32x4 o1 = *(i32x4*)&h_out[4];
      coh_store32((uint32*)(H + (size_t)t*MM + wg*8), o0, o1);
    }
  }
}

extern "C" void kernel_launch(void* const* d_in, const int* in_sizes, int n_in,
                              void* d_out, int out_size, void* d_ws, size_t ws_size,
                              hipStream_t stream) {
  (void)in_sizes; (void)n_in; (void)out_size;

  const float* X   = (const float*)d_in[0];
  const float* Wx1 = (const float*)d_in[1];
  const float* Wh1 = (const float*)d_in[2];
  const float* bh1 = (const float*)d_in[3];
  const float* h01 = (const float*)d_in[4];
  const float* Wx2 = (const float*)d_in[5];
  const float* Wh2 = (const float*)d_in[6];
  const float* bh2 = (const float*)d_in[7];
  const float* h02 = (const float*)d_in[8];
  const float* Wl  = (const float*)d_in[9];
  const float* bl  = (const float*)d_in[10];
  float* out = (float*)d_out;

  const size_t NBUF = (size_t)TT * MM;
  dim3 blk(256);

  if (ws_size >= 3 * NBUF * sizeof(float)) {
    // layout: [Xp1 f32 64MB][H2f f32 64MB][H1b bf16 32MB][H2b bf16 32MB]
    float*  Xp1 = (float*)d_ws;
    float*  H2f = Xp1 + NBUF;
    uint32* H1b = (uint32*)(H2f + NBUF);
    uint32* H2b = H1b + (size_t)TT * 1024;

    (void)hipMemsetAsync(H1b, 0xFF, 2 * (size_t)TT * 1024 * sizeof(uint32), stream);

    gemm_bias_f32<<<dim3(MM/128, TT/128), blk, 0, stream>>>(X, Wx1, bh1, Xp1, TT, MM, DD);

    {
      const float* xp = Xp1; uint32* h1b = H1b; uint32* h2b = H2b; float* h2f = H2f;
      const float* wh1 = Wh1; const float* wx2 = Wx2; const float* wh2 = Wh2;
      const float* h01p = h01; const float* h02p = h02; const float* bh2p = bh2;
      void* args[] = {&xp, &h1b, &h2b, &h2f, &wh1, &wx2, &wh2, &h01p, &h02p, &bh2p};
      (void)hipLaunchCooperativeKernel((const void*)rnn_fused, dim3(256), blk, args, 0, stream);
    }

    gemm_bias_f32<<<dim3(KK/128, TT/128), blk, 0, stream>>>(H2f, Wl, bl, out, TT, KK, MM);
  } else {
    // ---- fallback: R3 two-scan path ----
    float* bufA = (float*)d_ws;
    float* bufB = bufA + NBUF;

    (void)hipMemsetAsync(bufB, 0xFF, NBUF * sizeof(float), stream);
    gemm_bias_f32<<<dim3(MM/128, TT/128), blk, 0, stream>>>(X, Wx1, bh1, bufA, TT, MM, DD);
    {
      const float* xp = bufA; float* h = bufB; const float* wh = Wh1; const float* h0p = h01;
      void* args[] = {&xp, &h, &wh, &h0p};
      (void)hipLaunchCooperativeKernel((const void*)rnn_scan_f32, dim3(256), blk, args, 0, stream);
    }
    gemm_bias_f32<<<dim3(MM/128, TT/128), blk, 0, stream>>>(bufB, Wx2, bh2, bufA, TT, MM, MM);
    (void)hipMemsetAsync(bufB, 0xFF, NBUF * sizeof(float), stream);
    {
      const float* xp = bufA; float* h = bufB; const float* wh = Wh2; const float* h0p = h02;
      void* args[] = {&xp, &h, &wh, &h0p};
      (void)hipLaunchCooperativeKernel((const void*)rnn_scan_f32, dim3(256), blk, args, 0, stream);
    }
    gemm_bias_f32<<<dim3(KK/128, TT/128), blk, 0, stream>>>(bufA, Wl, bl, out, TT, KK, MM);
  }
}